// Round 4
// baseline (275.360 us; speedup 1.0000x reference)
//
#include <hip/hip_runtime.h>
#include <math.h>

// Problem constants (from reference)
#define GRID_N 544          // NUM_GRID = ceil(128*4.2/16)*16
#define BATCH  8
#define NPTS   2048
#define MPTS   2048
#define XMIN_F (-2.1f)
#define STEP_F (4.2f / 543.0f)   // linspace step, endpoint inclusive

// Workspace layout (floats):
// prm: [0..7]=a_mean (0.5*exp(-2*sigma)), [8..15]=a_sig,
//      [16..79]=S (8x8 = sig_W sig_W^T), [80..87]=u (sig_W@sig_b),
//      [88]=s0 (sig_b.sig_b), [89]=flag_all_16_scales_identical
#define PRM_OFF 0
#define H_OFF   128                        // h: B*G*8 = 34816 floats
#define FS_OFF  (H_OFF + BATCH*GRID_N*8)   // feat_sig: B*M*8 = 131072
#define P_OFF   (FS_OFF + BATCH*MPTS*8)    // P = feat_sig@S + u: B*M*8
#define CM_OFF  (P_OFF + BATCH*MPTS*8)     // c_m: B*M

// ------------------------------------------------------------- K1: encoder
// Blocks g<GRID_N: one block per (b,g): F0=sum_n w0, F1=sum_n y*w1, tiny MLP
// -> h[b,g,0..7].  Block (g==GRID_N, b==0): parameter precompute (S,u,s0,
// RBF scale coeffs, fused flag) — hides behind the 4352 encode blocks.
__global__ __launch_bounds__(256) void k_encode(
    const float* __restrict__ x, const float* __restrict__ y,
    const float* __restrict__ enc_sigma,
    const float* __restrict__ enc_W, const float* __restrict__ enc_b,
    const float* __restrict__ rho_W, const float* __restrict__ rho_b,
    const float* __restrict__ mean_sigma, const float* __restrict__ sig_sigma,
    const float* __restrict__ sig_W, const float* __restrict__ sig_b,
    float* __restrict__ prm, float* __restrict__ h_out) {
  int b = blockIdx.y, g = blockIdx.x, t = threadIdx.x;

  if (g == GRID_N) {                 // ---- parameter block ----
    if (b != 0) return;
    __shared__ float part[256];
    // S[i][j] = sig_W[i,:].sig_W[j,:]  (64 pairs x 4 k-slices of 256)
    {
      int pair = t >> 2, q = t & 3;
      int i = pair >> 3, j = pair & 7;
      float s = 0.f;
      int k0 = q * 256;
      for (int k = k0; k < k0 + 256; ++k) s += sig_W[i*1024+k] * sig_W[j*1024+k];
      part[t] = s;
      __syncthreads();
      if (q == 0) prm[16 + pair] = part[t] + part[t+1] + part[t+2] + part[t+3];
      __syncthreads();
    }
    // u[ch] = sig_W[ch,:].sig_b  (32 threads per channel)
    {
      int ch = t >> 5, lane = t & 31;
      float s = 0.f;
      for (int k = lane; k < 1024; k += 32) s += sig_W[ch*1024+k] * sig_b[k];
      part[t] = s;
      __syncthreads();
      if (lane == 0) {
        float acc = 0.f;
        for (int k = 0; k < 32; ++k) acc += part[(ch<<5)+k];
        prm[80 + ch] = acc;
      }
      __syncthreads();
    }
    // s0 = sig_b.sig_b
    if (t < 32) {
      float v = 0.f;
      for (int k = t; k < 1024; k += 32) v += sig_b[k] * sig_b[k];
      part[t] = v;
    }
    __syncthreads();
    if (t == 0) {
      float v = 0.f;
      for (int k = 0; k < 32; ++k) v += part[k];
      prm[88] = v;
    } else if (t == 1) {
      bool f = true;
      for (int c = 0; c < 8; ++c) {
        prm[c]     = 0.5f * __expf(-2.f * mean_sigma[c]);
        prm[8 + c] = 0.5f * __expf(-2.f * sig_sigma[c]);
        if (mean_sigma[c] != mean_sigma[0] || sig_sigma[c] != sig_sigma[0]) f = false;
      }
      if (mean_sigma[0] != sig_sigma[0]) f = false;
      prm[89] = f ? 1.f : 0.f;
    }
    return;
  }

  // ---- encode block ----
  float gv = XMIN_F + (float)g * STEP_F;
  float es0 = enc_sigma[0], es1 = enc_sigma[1];
  float a0 = 0.5f * __expf(-2.f * es0);
  float a1 = 0.5f * __expf(-2.f * es1);
  bool uni = (es0 == es1);
  const float4* x4 = (const float4*)(x + (size_t)b * NPTS);
  const float4* y4 = (const float4*)(y + (size_t)b * NPTS);
  float s0 = 0.f, s1 = 0.f;
  #pragma unroll
  for (int i = 0; i < 2; ++i) {
    int n = i * 256 + t;
    float4 xv = x4[n], yv = y4[n];
    float dx, d, w;
    dx = xv.x - gv; d = dx*dx; w = __expf(-d*a0); s0 += w;
    s1 += yv.x * (uni ? w : __expf(-d*a1));
    dx = xv.y - gv; d = dx*dx; w = __expf(-d*a0); s0 += w;
    s1 += yv.y * (uni ? w : __expf(-d*a1));
    dx = xv.z - gv; d = dx*dx; w = __expf(-d*a0); s0 += w;
    s1 += yv.z * (uni ? w : __expf(-d*a1));
    dx = xv.w - gv; d = dx*dx; w = __expf(-d*a0); s0 += w;
    s1 += yv.w * (uni ? w : __expf(-d*a1));
  }
  #pragma unroll
  for (int off = 32; off > 0; off >>= 1) {
    s0 += __shfl_down(s0, off);
    s1 += __shfl_down(s1, off);
  }
  __shared__ float w0s[4], w1s[4];
  int wid = t >> 6;
  if ((t & 63) == 0) { w0s[wid] = s0; w1s[wid] = s1; }
  __syncthreads();
  if (t == 0) {
    float den = w0s[0] + w0s[1] + w0s[2] + w0s[3];
    float conv = w1s[0] + w1s[1] + w1s[2] + w1s[3];
    float F0 = den, F1 = conv / (den + 1e-8f);
    float hh[8];
    #pragma unroll
    for (int jj = 0; jj < 8; ++jj) {
      float z = F0 * enc_W[jj] + F1 * enc_W[8 + jj] + enc_b[jj];
      hh[jj] = 1.f / (1.f + __expf(-z));
    }
    #pragma unroll
    for (int jj = 0; jj < 8; ++jj) {
      float v = rho_b[jj];
      #pragma unroll
      for (int ii = 0; ii < 8; ++ii) v += hh[ii] * rho_W[ii*8 + jj];
      h_out[((size_t)b * GRID_N + g) * 8 + jj] = v;
    }
  }
}

// ------------------------------------------------------------- K2: decoder feats
// block = 256 = 64 m-lanes x 4 g-slices (136 g each).  [R2-known-good shape]
// Computes mean output, feat_sig, P = feat_sig@S + u, c_m = feat_sig.u + s0.
// Fast path (all 16 RBF scales identical): 1 exp + 8 FMA per g, fm == fs.
__global__ __launch_bounds__(256) void k_feat(
    const float* __restrict__ x_out, const float* __restrict__ mean_W,
    const float* __restrict__ mean_b, const float* __restrict__ prm,
    const float* __restrict__ h, float* __restrict__ mean_out,
    float* __restrict__ fS, float* __restrict__ Pv, float* __restrict__ cm) {
  int b = blockIdx.y, t = threadIdx.x;
  int ml = t & 63, slice = t >> 6;
  int m = blockIdx.x * 64 + ml;
  float xo = x_out[(size_t)b * MPTS + m];
  bool fused = prm[89] != 0.f;
  float accm[8] = {0,0,0,0,0,0,0,0};
  float accs[8] = {0,0,0,0,0,0,0,0};
  const float* hb = h + (size_t)b * GRID_N * 8;
  const float4* h4 = (const float4*)hb;
  int gbase = slice * 136;
  if (fused) {
    float a = prm[0];  // == all of a_mean, a_sig
    for (int gg = 0; gg < 136; ++gg) {
      int g = gbase + gg;
      float gv = XMIN_F + (float)g * STEP_F;
      float dx = gv - xo;
      float w = __expf(-(dx*dx) * a);
      float4 h0 = h4[g*2], h1 = h4[g*2+1];
      accm[0] += h0.x * w; accm[1] += h0.y * w;
      accm[2] += h0.z * w; accm[3] += h0.w * w;
      accm[4] += h1.x * w; accm[5] += h1.y * w;
      accm[6] += h1.z * w; accm[7] += h1.w * w;
    }
  } else {
    float am[8], asg[8];
    #pragma unroll
    for (int c = 0; c < 8; ++c) { am[c] = prm[c]; asg[c] = prm[8 + c]; }
    for (int gg = 0; gg < 136; ++gg) {
      int g = gbase + gg;
      float gv = XMIN_F + (float)g * STEP_F;
      float dx = gv - xo;
      float d = dx * dx;
      #pragma unroll
      for (int c = 0; c < 8; ++c) {
        float hv = hb[g*8 + c];
        accm[c] += hv * __expf(-d * am[c]);
        accs[c] += hv * __expf(-d * asg[c]);
      }
    }
  }
  __shared__ float red[256 * 17];   // stride 17: bank-conflict-free
  #pragma unroll
  for (int c = 0; c < 8; ++c) {
    red[t*17 + c] = accm[c];
    if (!fused) red[t*17 + 8 + c] = accs[c];
  }
  __syncthreads();
  if (t < 64) {
    int mm = blockIdx.x * 64 + t;
    float fm[8], fs[8];
    #pragma unroll
    for (int c = 0; c < 8; ++c) {
      fm[c] = red[t*17+c] + red[(t+64)*17+c] + red[(t+128)*17+c] + red[(t+192)*17+c];
    }
    if (fused) {
      #pragma unroll
      for (int c = 0; c < 8; ++c) fs[c] = fm[c];
    } else {
      #pragma unroll
      for (int c = 0; c < 8; ++c) {
        fs[c] = red[t*17+8+c] + red[(t+64)*17+8+c] + red[(t+128)*17+8+c] + red[(t+192)*17+8+c];
      }
    }
    float mv = mean_b[0];
    #pragma unroll
    for (int c = 0; c < 8; ++c) mv += fm[c] * mean_W[c];
    mean_out[(size_t)b * MPTS + mm] = mv;
    float cmv = prm[88];
    #pragma unroll
    for (int c = 0; c < 8; ++c) cmv += fs[c] * prm[80 + c];
    cm[(size_t)b * MPTS + mm] = cmv;
    size_t base = ((size_t)b * MPTS + mm) * 8;
    #pragma unroll
    for (int c2 = 0; c2 < 8; ++c2) {
      float p = prm[80 + c2];
      #pragma unroll
      for (int c = 0; c < 8; ++c) p += fs[c] * prm[16 + c*8 + c2];
      Pv[base + c2] = p;
    }
    #pragma unroll
    for (int c = 0; c < 8; ++c) fS[base + c] = fs[c];
  }
}

// ------------------------------------------------------------- K3: covariance
// cov[b,m,n] = P[b,m,:].f[b,n,:] + c_m (+ noise on diag). Write-BW bound.
// [R2-known-good layout] thread t owns 8 contiguous columns n0=8t; 16 m-rows
// per block; per-thread 32 B contiguous, per-wave 2 KB dense region.
// Diagonal noise via per-j compares (no dynamic register indexing).
__global__ __launch_bounds__(256) void k_cov(
    const float* __restrict__ fS, const float* __restrict__ Pv,
    const float* __restrict__ cm, const float* __restrict__ noise_scale,
    float* __restrict__ cov) {
  int b = blockIdx.y, t = threadIdx.x;
  int mt = blockIdx.x * 16;
  int n0 = t * 8;
  float noise = __expf(noise_scale[0]);
  // load f for my 8 columns (8 rows x 8 channels = 16 float4)
  float fn[8][8];
  const float4* fv = (const float4*)(fS + ((size_t)b * MPTS + n0) * 8);
  #pragma unroll
  for (int j = 0; j < 8; ++j) {
    float4 lo = fv[j*2], hi = fv[j*2+1];
    fn[j][0]=lo.x; fn[j][1]=lo.y; fn[j][2]=lo.z; fn[j][3]=lo.w;
    fn[j][4]=hi.x; fn[j][5]=hi.y; fn[j][6]=hi.z; fn[j][7]=hi.w;
  }
  __shared__ float Ps[16*8];
  __shared__ float Cs[16];
  if (t < 128) Ps[t] = Pv[((size_t)b * MPTS + mt) * 8 + t];
  if (t < 16)  Cs[t] = cm[(size_t)b * MPTS + mt + t];
  __syncthreads();
  #pragma unroll 1
  for (int mi = 0; mi < 16; ++mi) {
    float p[8];
    #pragma unroll
    for (int c = 0; c < 8; ++c) p[c] = Ps[mi*8 + c];
    float cc = Cs[mi];
    int mg = mt + mi;
    float o[8];
    #pragma unroll
    for (int j = 0; j < 8; ++j) {
      float acc = cc;
      #pragma unroll
      for (int c = 0; c < 8; ++c) acc += p[c] * fn[j][c];
      if (mg == n0 + j) acc += noise;   // cndmask, no dynamic indexing
      o[j] = acc;
    }
    float4* outp = (float4*)(cov + ((size_t)b * MPTS + mg) * MPTS + n0);
    outp[0] = make_float4(o[0], o[1], o[2], o[3]);
    outp[1] = make_float4(o[4], o[5], o[6], o[7]);
  }
}

extern "C" void kernel_launch(void* const* d_in, const int* in_sizes, int n_in,
                              void* d_out, int out_size, void* d_ws, size_t ws_size,
                              hipStream_t stream) {
  const float* x          = (const float*)d_in[0];
  const float* y          = (const float*)d_in[1];
  const float* x_out      = (const float*)d_in[2];
  const float* enc_sigma  = (const float*)d_in[3];
  const float* enc_W      = (const float*)d_in[4];
  const float* enc_b      = (const float*)d_in[5];
  const float* rho_W      = (const float*)d_in[6];
  const float* rho_b      = (const float*)d_in[7];
  const float* mean_sigma = (const float*)d_in[8];
  const float* mean_W     = (const float*)d_in[9];
  const float* mean_b     = (const float*)d_in[10];
  const float* sig_sigma  = (const float*)d_in[11];
  const float* sig_W      = (const float*)d_in[12];
  const float* sig_b      = (const float*)d_in[13];
  const float* noise_sc   = (const float*)d_in[14];

  float* wsf = (float*)d_ws;
  float* prm  = wsf + PRM_OFF;
  float* hbuf = wsf + H_OFF;
  float* fSb  = wsf + FS_OFF;
  float* Pb   = wsf + P_OFF;
  float* cmb  = wsf + CM_OFF;

  float* mean_out = (float*)d_out;                   // B*M floats
  float* cov_out  = mean_out + (size_t)BATCH * MPTS; // B*M*M floats

  k_encode<<<dim3(GRID_N + 1, BATCH), 256, 0, stream>>>(
      x, y, enc_sigma, enc_W, enc_b, rho_W, rho_b,
      mean_sigma, sig_sigma, sig_W, sig_b, prm, hbuf);
  k_feat<<<dim3(MPTS/64, BATCH), 256, 0, stream>>>(x_out, mean_W, mean_b, prm,
                                                   hbuf, mean_out, fSb, Pb, cmb);
  k_cov<<<dim3(MPTS/16, BATCH), 256, 0, stream>>>(fSb, Pb, cmb, noise_sc, cov_out);
}

// Round 5
// 217.704 us; speedup vs baseline: 1.2648x; 1.2648x over previous
//
#include <hip/hip_runtime.h>
#include <math.h>

// Problem constants (from reference)
#define GRID_N 544          // NUM_GRID = ceil(128*4.2/16)*16
#define BATCH  8
#define NPTS   2048
#define MPTS   2048
#define XMIN_F (-2.1f)
#define STEP_F (4.2f / 543.0f)   // linspace step, endpoint inclusive

typedef float v4f __attribute__((ext_vector_type(4)));

// Workspace layout (floats):
// prm: [0..7]=a_mean (0.5*exp(-2*sigma)), [8..15]=a_sig,
//      [16..79]=S (8x8 = sig_W sig_W^T), [80..87]=u (sig_W@sig_b),
//      [88]=s0 (sig_b.sig_b), [89]=flag_all_16_scales_identical
#define PRM_OFF 0
#define H_OFF   128                         // h: B*G*8 = 34816 floats
#define FST_OFF (H_OFF + BATCH*GRID_N*8)    // fS transposed planes [b][c][M]: B*8*M
#define P_OFF   (FST_OFF + BATCH*8*MPTS)    // P = feat_sig@S + u: B*M*8 (row-major)
#define CM_OFF  (P_OFF + BATCH*MPTS*8)      // c_m: B*M

// ------------------------------------------------------------- K1: encoder
// Blocks g<GRID_N: one block per (b,g): F0=sum_n w0, F1=sum_n y*w1, tiny MLP
// -> h[b,g,0..7].  Block (g==GRID_N, b==0): parameter precompute — hides
// behind the 4352 encode blocks.
__global__ __launch_bounds__(256) void k_encode(
    const float* __restrict__ x, const float* __restrict__ y,
    const float* __restrict__ enc_sigma,
    const float* __restrict__ enc_W, const float* __restrict__ enc_b,
    const float* __restrict__ rho_W, const float* __restrict__ rho_b,
    const float* __restrict__ mean_sigma, const float* __restrict__ sig_sigma,
    const float* __restrict__ sig_W, const float* __restrict__ sig_b,
    float* __restrict__ prm, float* __restrict__ h_out) {
  int b = blockIdx.y, g = blockIdx.x, t = threadIdx.x;

  if (g == GRID_N) {                 // ---- parameter block ----
    if (b != 0) return;
    __shared__ float part[256];
    // S[i][j] = sig_W[i,:].sig_W[j,:]  (64 pairs x 4 k-slices of 256)
    {
      int pair = t >> 2, q = t & 3;
      int i = pair >> 3, j = pair & 7;
      float s = 0.f;
      int k0 = q * 256;
      for (int k = k0; k < k0 + 256; ++k) s += sig_W[i*1024+k] * sig_W[j*1024+k];
      part[t] = s;
      __syncthreads();
      if (q == 0) prm[16 + pair] = part[t] + part[t+1] + part[t+2] + part[t+3];
      __syncthreads();
    }
    // u[ch] = sig_W[ch,:].sig_b  (32 threads per channel)
    {
      int ch = t >> 5, lane = t & 31;
      float s = 0.f;
      for (int k = lane; k < 1024; k += 32) s += sig_W[ch*1024+k] * sig_b[k];
      part[t] = s;
      __syncthreads();
      if (lane == 0) {
        float acc = 0.f;
        for (int k = 0; k < 32; ++k) acc += part[(ch<<5)+k];
        prm[80 + ch] = acc;
      }
      __syncthreads();
    }
    // s0 = sig_b.sig_b
    if (t < 32) {
      float v = 0.f;
      for (int k = t; k < 1024; k += 32) v += sig_b[k] * sig_b[k];
      part[t] = v;
    }
    __syncthreads();
    if (t == 0) {
      float v = 0.f;
      for (int k = 0; k < 32; ++k) v += part[k];
      prm[88] = v;
    } else if (t == 1) {
      bool f = true;
      for (int c = 0; c < 8; ++c) {
        prm[c]     = 0.5f * __expf(-2.f * mean_sigma[c]);
        prm[8 + c] = 0.5f * __expf(-2.f * sig_sigma[c]);
        if (mean_sigma[c] != mean_sigma[0] || sig_sigma[c] != sig_sigma[0]) f = false;
      }
      if (mean_sigma[0] != sig_sigma[0]) f = false;
      prm[89] = f ? 1.f : 0.f;
    }
    return;
  }

  // ---- encode block ----
  float gv = XMIN_F + (float)g * STEP_F;
  float es0 = enc_sigma[0], es1 = enc_sigma[1];
  float a0 = 0.5f * __expf(-2.f * es0);
  float a1 = 0.5f * __expf(-2.f * es1);
  bool uni = (es0 == es1);
  const float4* x4 = (const float4*)(x + (size_t)b * NPTS);
  const float4* y4 = (const float4*)(y + (size_t)b * NPTS);
  float s0 = 0.f, s1 = 0.f;
  #pragma unroll
  for (int i = 0; i < 2; ++i) {
    int n = i * 256 + t;
    float4 xv = x4[n], yv = y4[n];
    float dx, d, w;
    dx = xv.x - gv; d = dx*dx; w = __expf(-d*a0); s0 += w;
    s1 += yv.x * (uni ? w : __expf(-d*a1));
    dx = xv.y - gv; d = dx*dx; w = __expf(-d*a0); s0 += w;
    s1 += yv.y * (uni ? w : __expf(-d*a1));
    dx = xv.z - gv; d = dx*dx; w = __expf(-d*a0); s0 += w;
    s1 += yv.z * (uni ? w : __expf(-d*a1));
    dx = xv.w - gv; d = dx*dx; w = __expf(-d*a0); s0 += w;
    s1 += yv.w * (uni ? w : __expf(-d*a1));
  }
  #pragma unroll
  for (int off = 32; off > 0; off >>= 1) {
    s0 += __shfl_down(s0, off);
    s1 += __shfl_down(s1, off);
  }
  __shared__ float w0s[4], w1s[4];
  int wid = t >> 6;
  if ((t & 63) == 0) { w0s[wid] = s0; w1s[wid] = s1; }
  __syncthreads();
  if (t == 0) {
    float den = w0s[0] + w0s[1] + w0s[2] + w0s[3];
    float conv = w1s[0] + w1s[1] + w1s[2] + w1s[3];
    float F0 = den, F1 = conv / (den + 1e-8f);
    float hh[8];
    #pragma unroll
    for (int jj = 0; jj < 8; ++jj) {
      float z = F0 * enc_W[jj] + F1 * enc_W[8 + jj] + enc_b[jj];
      hh[jj] = 1.f / (1.f + __expf(-z));
    }
    #pragma unroll
    for (int jj = 0; jj < 8; ++jj) {
      float v = rho_b[jj];
      #pragma unroll
      for (int ii = 0; ii < 8; ++ii) v += hh[ii] * rho_W[ii*8 + jj];
      h_out[((size_t)b * GRID_N + g) * 8 + jj] = v;
    }
  }
}

// ------------------------------------------------------------- K2: decoder feats
// block = 256 = 64 m-lanes x 4 g-slices (136 g each).
// Computes mean output, fS (TRANSPOSED channel planes), P = fs@S + u,
// c_m = fs.u + s0.  Fast path: all 16 RBF scales identical -> 1 exp, fm==fs.
__global__ __launch_bounds__(256) void k_feat(
    const float* __restrict__ x_out, const float* __restrict__ mean_W,
    const float* __restrict__ mean_b, const float* __restrict__ prm,
    const float* __restrict__ h, float* __restrict__ mean_out,
    float* __restrict__ fSt, float* __restrict__ Pv, float* __restrict__ cm) {
  int b = blockIdx.y, t = threadIdx.x;
  int ml = t & 63, slice = t >> 6;
  int m = blockIdx.x * 64 + ml;
  float xo = x_out[(size_t)b * MPTS + m];
  bool fused = prm[89] != 0.f;
  float accm[8] = {0,0,0,0,0,0,0,0};
  float accs[8] = {0,0,0,0,0,0,0,0};
  const float* hb = h + (size_t)b * GRID_N * 8;
  const float4* h4 = (const float4*)hb;
  int gbase = slice * 136;
  if (fused) {
    float a = prm[0];  // == all of a_mean, a_sig
    for (int gg = 0; gg < 136; ++gg) {
      int g = gbase + gg;
      float gv = XMIN_F + (float)g * STEP_F;
      float dx = gv - xo;
      float w = __expf(-(dx*dx) * a);
      float4 h0 = h4[g*2], h1 = h4[g*2+1];
      accm[0] += h0.x * w; accm[1] += h0.y * w;
      accm[2] += h0.z * w; accm[3] += h0.w * w;
      accm[4] += h1.x * w; accm[5] += h1.y * w;
      accm[6] += h1.z * w; accm[7] += h1.w * w;
    }
  } else {
    float am[8], asg[8];
    #pragma unroll
    for (int c = 0; c < 8; ++c) { am[c] = prm[c]; asg[c] = prm[8 + c]; }
    for (int gg = 0; gg < 136; ++gg) {
      int g = gbase + gg;
      float gv = XMIN_F + (float)g * STEP_F;
      float dx = gv - xo;
      float d = dx * dx;
      #pragma unroll
      for (int c = 0; c < 8; ++c) {
        float hv = hb[g*8 + c];
        accm[c] += hv * __expf(-d * am[c]);
        accs[c] += hv * __expf(-d * asg[c]);
      }
    }
  }
  __shared__ float red[256 * 17];   // stride 17: bank-conflict-free
  #pragma unroll
  for (int c = 0; c < 8; ++c) {
    red[t*17 + c] = accm[c];
    if (!fused) red[t*17 + 8 + c] = accs[c];
  }
  __syncthreads();
  if (t < 64) {
    int mm = blockIdx.x * 64 + t;
    float fm[8], fs[8];
    #pragma unroll
    for (int c = 0; c < 8; ++c) {
      fm[c] = red[t*17+c] + red[(t+64)*17+c] + red[(t+128)*17+c] + red[(t+192)*17+c];
    }
    if (fused) {
      #pragma unroll
      for (int c = 0; c < 8; ++c) fs[c] = fm[c];
    } else {
      #pragma unroll
      for (int c = 0; c < 8; ++c) {
        fs[c] = red[t*17+8+c] + red[(t+64)*17+8+c] + red[(t+128)*17+8+c] + red[(t+192)*17+8+c];
      }
    }
    float mv = mean_b[0];
    #pragma unroll
    for (int c = 0; c < 8; ++c) mv += fm[c] * mean_W[c];
    mean_out[(size_t)b * MPTS + mm] = mv;
    float cmv = prm[88];
    #pragma unroll
    for (int c = 0; c < 8; ++c) cmv += fs[c] * prm[80 + c];
    cm[(size_t)b * MPTS + mm] = cmv;
    // P row-major
    size_t base = ((size_t)b * MPTS + mm) * 8;
    #pragma unroll
    for (int c2 = 0; c2 < 8; ++c2) {
      float p = prm[80 + c2];
      #pragma unroll
      for (int c = 0; c < 8; ++c) p += fs[c] * prm[16 + c*8 + c2];
      Pv[base + c2] = p;
    }
    // fS transposed: plane per channel -> dense loads in k_cov
    float* fp = fSt + (size_t)b * 8 * MPTS + mm;
    #pragma unroll
    for (int c = 0; c < 8; ++c) fp[c * MPTS] = fs[c];
  }
}

// ------------------------------------------------------------- K3: covariance
// cov[b,m,n] = P[b,m,:].f[:,n] + c_m (+ noise on diag).  Write-BW bound.
// Block: 256 threads, thread t owns 4 CONTIGUOUS cols [col0+4t, +4) -> each
// wave store = 64 x16B = 1KB dense.  Block covers 1024 cols x 32 rows.
// Inner: bursts of 8 rows computed into DISTINCT registers, then 8 stores
// issued back-to-back -> 8 stores in flight per wave (fixes the vmcnt(0)
// per-store serialization that held R4 at 1.4 TB/s).
__global__ __launch_bounds__(256) void k_cov(
    const float* __restrict__ fSt, const float* __restrict__ Pv,
    const float* __restrict__ cm, const float* __restrict__ noise_scale,
    float* __restrict__ cov) {
  int b = blockIdx.y, t = threadIdx.x;
  int half = blockIdx.x & 1, rt = blockIdx.x >> 1;
  int col = half * 1024 + 4 * t;
  int row0 = rt * 32;
  float noise = __expf(noise_scale[0]);
  // dense f loads: fn[c] = f[c][col..col+4)
  v4f fn[8];
  const float* fb = fSt + (size_t)b * 8 * MPTS;
  #pragma unroll
  for (int c = 0; c < 8; ++c)
    fn[c] = *(const v4f*)(fb + c * MPTS + col);
  __shared__ float Ps[32 * 8];
  __shared__ float Cs[32];
  Ps[t] = Pv[((size_t)b * MPTS + row0) * 8 + t];
  if (t < 32) Cs[t] = cm[(size_t)b * MPTS + row0 + t];
  __syncthreads();
  #pragma unroll 1
  for (int r8 = 0; r8 < 4; ++r8) {
    v4f o[8];
    #pragma unroll
    for (int i = 0; i < 8; ++i) {
      int mi = r8 * 8 + i;
      float cc = Cs[mi];
      float a0 = cc, a1 = cc, a2 = cc, a3 = cc;
      #pragma unroll
      for (int c = 0; c < 8; ++c) {
        float p = Ps[mi * 8 + c];
        a0 += p * fn[c].x; a1 += p * fn[c].y;
        a2 += p * fn[c].z; a3 += p * fn[c].w;
      }
      int mg = row0 + mi;
      if (mg == col)     a0 += noise;
      if (mg == col + 1) a1 += noise;
      if (mg == col + 2) a2 += noise;
      if (mg == col + 3) a3 += noise;
      o[i].x = a0; o[i].y = a1; o[i].z = a2; o[i].w = a3;
    }
    #pragma unroll
    for (int i = 0; i < 8; ++i) {
      int mi = r8 * 8 + i;
      v4f* dst = (v4f*)(cov + ((size_t)b * MPTS + row0 + mi) * MPTS + col);
      __builtin_nontemporal_store(o[i], dst);
    }
  }
}

extern "C" void kernel_launch(void* const* d_in, const int* in_sizes, int n_in,
                              void* d_out, int out_size, void* d_ws, size_t ws_size,
                              hipStream_t stream) {
  const float* x          = (const float*)d_in[0];
  const float* y          = (const float*)d_in[1];
  const float* x_out      = (const float*)d_in[2];
  const float* enc_sigma  = (const float*)d_in[3];
  const float* enc_W      = (const float*)d_in[4];
  const float* enc_b      = (const float*)d_in[5];
  const float* rho_W      = (const float*)d_in[6];
  const float* rho_b      = (const float*)d_in[7];
  const float* mean_sigma = (const float*)d_in[8];
  const float* mean_W     = (const float*)d_in[9];
  const float* mean_b     = (const float*)d_in[10];
  const float* sig_sigma  = (const float*)d_in[11];
  const float* sig_W      = (const float*)d_in[12];
  const float* sig_b      = (const float*)d_in[13];
  const float* noise_sc   = (const float*)d_in[14];

  float* wsf = (float*)d_ws;
  float* prm  = wsf + PRM_OFF;
  float* hbuf = wsf + H_OFF;
  float* fStb = wsf + FST_OFF;
  float* Pb   = wsf + P_OFF;
  float* cmb  = wsf + CM_OFF;

  float* mean_out = (float*)d_out;                   // B*M floats
  float* cov_out  = mean_out + (size_t)BATCH * MPTS; // B*M*M floats

  k_encode<<<dim3(GRID_N + 1, BATCH), 256, 0, stream>>>(
      x, y, enc_sigma, enc_W, enc_b, rho_W, rho_b,
      mean_sigma, sig_sigma, sig_W, sig_b, prm, hbuf);
  k_feat<<<dim3(MPTS/64, BATCH), 256, 0, stream>>>(x_out, mean_W, mean_b, prm,
                                                   hbuf, mean_out, fStb, Pb, cmb);
  k_cov<<<dim3(2 * (MPTS/32), BATCH), 256, 0, stream>>>(fStb, Pb, cmb, noise_sc,
                                                        cov_out);
}